// Round 2
// 60.495 us; speedup vs baseline: 1.1728x; 1.1728x over previous
//
#include <hip/hip_runtime.h>

#define N 2048
#define B 16
#define STRENGTH 0.1f
#define RADIUS 2310.0f
#define JCHUNKS 16        // j-chunks per batch in kernel 1 (256 blocks total)
#define BLK1 256          // 4 waves/block -> 1 block per CU, all 4 SIMDs busy
#define BLK2 256

// Kernel 1: per (batch, j-chunk) block. d[b,j] = sum_i |x[b,i]-x[b,j]|.
// The i-sum is split across TWO waves per j-group in a way that is
// bit-identical to the passing rounds:
//   waves 0/1 (half=0) run chains a0..a3 over even float4 slots and form
//     sA = (a0+a1)+(a2+a3)
//   waves 2/3 (half=1) run chains a4..a7 over odd float4 slots and form
//     sB = (a4+a5)+(a6+a7)
//   d = sA + sB   == ((a0+a1)+(a2+a3))+((a4+a5)+(a6+a7))  (original order)
// Waves 0/1 hold j = lane exactly as the previous 128-thread version did,
// so the w/wx butterfly tree and partials layout are unchanged bit-for-bit.
// Block 0 thread 0 also zeroes d_out so kernel 2 can atomicAdd into it.
__global__ __launch_bounds__(BLK1) void repulsion_dist_kernel(
    const float* __restrict__ x, float* __restrict__ partials,
    float* __restrict__ out) {
  __shared__ float4 xs4[N / 4];      // 8 KiB
  __shared__ float sB_s[128];        // cross-wave half-sums
  __shared__ float sw_s[2], swx_s[2];
  const int b = blockIdx.x >> 4;      // / JCHUNKS
  const int chunk = blockIdx.x & 15;  // % JCHUNKS
  const int tid = threadIdx.x;
  if (blockIdx.x == 0 && tid == 0) out[0] = 0.f;  // k2 runs strictly after k1
  const float4* __restrict__ xb4 = (const float4*)(x + b * N);

#pragma unroll
  for (int k = 0; k < N / 4 / BLK1; ++k) xs4[tid + BLK1 * k] = xb4[tid + BLK1 * k];
  __syncthreads();

  const int wave = tid >> 6, lane = tid & 63;
  const int jg = wave & 1;    // j-group: 0 -> j 0..63 of chunk, 1 -> j 64..127
  const int half = wave >> 1; // i-half: 0 -> even float4 slots, 1 -> odd
  const int j = chunk * 128 + jg * 64 + lane;
  const float xj = ((const float*)xs4)[j];

  float a0 = 0.f, a1 = 0.f, a2 = 0.f, a3 = 0.f;
#pragma unroll 8
  for (int t = 0; t < N / 8; ++t) {   // 256 iterations, 1 broadcast float4 each
    const float4 v = xs4[2 * t + half];
    a0 += fabsf(v.x - xj);
    a1 += fabsf(v.y - xj);
    a2 += fabsf(v.z - xj);
    a3 += fabsf(v.w - xj);
  }
  const float s = (a0 + a1) + (a2 + a3);

  if (half) sB_s[jg * 64 + lane] = s;
  __syncthreads();

  if (!half) {
    const float d = s + sB_s[jg * 64 + lane];  // sA + sB, original combine order
    float w = (d < RADIUS) ? STRENGTH : 0.f;
    float wx = w * xj;
#pragma unroll
    for (int m = 32; m >= 1; m >>= 1) {
      w += __shfl_xor(w, m, 64);
      wx += __shfl_xor(wx, m, 64);
    }
    if (lane == 0) { sw_s[jg] = w; swx_s[jg] = wx; }
  }
  __syncthreads();
  if (tid == 0) {
    partials[blockIdx.x * 2 + 0] = sw_s[0] + sw_s[1];
    partials[blockIdx.x * 2 + 1] = swx_s[0] + swx_s[1];
  }
}

// Kernel 2: one block per batch (16 blocks). Combine the 16 chunk partials,
// compute ||Sxw - Sw*x[b,:]||_2, atomicAdd(norm/B) into out.  (Unchanged.)
__global__ __launch_bounds__(BLK2) void repulsion_norm_kernel(
    const float* __restrict__ x, const float* __restrict__ partials,
    float* __restrict__ out) {
  const int b = blockIdx.x;
  const int tid = threadIdx.x;  // 0..255

  // Sum the 16 (sw, swx) chunk partials on wave 0, broadcast via LDS.
  __shared__ float sw_bc, swx_bc;
  if (tid < 64) {
    float sw = 0.f, swx = 0.f;
    if (tid < JCHUNKS) {
      sw  = partials[(b * JCHUNKS + tid) * 2 + 0];
      swx = partials[(b * JCHUNKS + tid) * 2 + 1];
    }
#pragma unroll
    for (int m = 8; m >= 1; m >>= 1) {
      sw += __shfl_xor(sw, m, 16);
      swx += __shfl_xor(swx, m, 16);
    }
    if (tid == 0) { sw_bc = sw; swx_bc = swx; }
  }
  __syncthreads();
  const float sw = sw_bc, swx = swx_bc;

  const float4* __restrict__ xb4 = (const float4*)(x + b * N);
  float acc = 0.f;
#pragma unroll
  for (int t = 0; t < N / 4 / BLK2; ++t) {  // 2 float4 per thread
    const float4 v = xb4[t * BLK2 + tid];
    float r0 = swx - sw * v.x; acc = fmaf(r0, r0, acc);
    float r1 = swx - sw * v.y; acc = fmaf(r1, r1, acc);
    float r2 = swx - sw * v.z; acc = fmaf(r2, r2, acc);
    float r3 = swx - sw * v.w; acc = fmaf(r3, r3, acc);
  }
#pragma unroll
  for (int m = 32; m >= 1; m >>= 1) acc += __shfl_xor(acc, m, 64);

  __shared__ float wsum[BLK2 / 64];
  const int wave = tid >> 6, lane = tid & 63;
  if (lane == 0) wsum[wave] = acc;
  __syncthreads();
  if (tid == 0) {
    const float tot = (wsum[0] + wsum[1]) + (wsum[2] + wsum[3]);
    atomicAdd(out, sqrtf(tot) * (1.0f / (float)B));
  }
}

extern "C" void kernel_launch(void* const* d_in, const int* in_sizes, int n_in,
                              void* d_out, int out_size, void* d_ws, size_t ws_size,
                              hipStream_t stream) {
  const float* x = (const float*)d_in[0];
  float* partials = (float*)d_ws;  // B*JCHUNKS*2 floats = 2 KiB
  float* out = (float*)d_out;
  repulsion_dist_kernel<<<B * JCHUNKS, BLK1, 0, stream>>>(x, partials, out);
  repulsion_norm_kernel<<<B, BLK2, 0, stream>>>(x, partials, out);
}